// Round 9
// baseline (166.552 us; speedup 1.0000x reference)
//
#include <hip/hip_runtime.h>

typedef unsigned short u16;
typedef unsigned int   u32;

using bf16x8 = __attribute__((ext_vector_type(8))) __bf16;
using bf16x4 = __attribute__((ext_vector_type(4))) __bf16;
using f32x4  = __attribute__((ext_vector_type(4))) float;
using s16x4  = __attribute__((ext_vector_type(4))) short;

#define NH    16
#define DKH   64
#define SEQ   2048
#define BAT   2
#define DMOD  1024

// 0.125 (1/sqrt(dk)) * log2(e): scores in log2 domain -> p = exp2(s)
#define QSCALE 0.18033688011112042f

__device__ __forceinline__ u16 f2bf(float f) {
  union { float f; u32 u; } v; v.f = f;
  u32 r = v.u + 0x7fffu + ((v.u >> 16) & 1u);
  return (u16)(r >> 16);
}

__device__ __forceinline__ u32 pack2bf(float a, float b) {
  union { float f; u32 u; } x, y; x.f = a; y.f = b;
  u32 ua = x.u + 0x7fffu + ((x.u >> 16) & 1u);
  u32 ub = y.u + 0x7fffu + ((y.u >> 16) & 1u);
  return __builtin_amdgcn_perm(ub, ua, 0x07060302u);
}

// compiler emits v_cvt_pk_bf16_f32 pairs
__device__ __forceinline__ s16x4 pk4bf(float a, float b, float c, float d) {
  union { bf16x4 bv; s16x4 sv; } u;
  u.bv[0] = (__bf16)a; u.bv[1] = (__bf16)b; u.bv[2] = (__bf16)c; u.bv[3] = (__bf16)d;
  return u.sv;
}

#if __has_builtin(__builtin_amdgcn_exp2f)
#define EXP2(x) __builtin_amdgcn_exp2f(x)
#else
#define EXP2(x) exp2f(x)
#endif

#if __has_builtin(__builtin_amdgcn_mfma_f32_16x16x16bf16_1k)
__device__ __forceinline__ f32x4 mfma16(s16x4 a, s16x4 b, f32x4 c) {
  return __builtin_amdgcn_mfma_f32_16x16x16bf16_1k(a, b, c, 0, 0, 0);
}
#else
__device__ __forceinline__ f32x4 mfma16(s16x4 a, s16x4 b, f32x4 c) {
  f32x4 d;
  asm volatile("v_mfma_f32_16x16x16_bf16 %0, %1, %2, %3\n\ts_nop 7\n\ts_nop 7"
               : "=v"(d) : "v"(a), "v"(b), "v"(c));
  return d;
}
#endif

// async global->LDS, 16B per lane. Dest must be linear in tid within each wave.
typedef const __attribute__((address_space(1))) u32 glb_u32;
typedef __attribute__((address_space(3))) u32 lds_u32;
__device__ __forceinline__ void gload16(const u16* g, u16* l) {
  __builtin_amdgcn_global_load_lds((glb_u32*)(const void*)g, (lds_u32*)(void*)l, 16, 0, 0);
}

// -------- fused prep: 4x weight transpose+cvt (z<4) + x fp32->bf16 (z==4) --------
// Round-9: merged transpose_all + convert_x -> one launch (one less dispatch gap).
__global__ __launch_bounds__(256) void prep(const float* __restrict__ Wq,
                                            const float* __restrict__ Wk,
                                            const float* __restrict__ Wv,
                                            const float* __restrict__ Wo,
                                            u16* __restrict__ Wt,
                                            const float* __restrict__ x,
                                            u16* __restrict__ xb) {
  const int z = blockIdx.z;
  if (z < 4) {
    __shared__ u16 t[32][33];
    const float* W = z == 0 ? Wq : z == 1 ? Wk : z == 2 ? Wv : Wo;
    u16* o = Wt + (size_t)z * DMOD * DMOD;
    int bx = blockIdx.x * 32, by = blockIdx.y * 32;
    int tx = threadIdx.x, ty = threadIdx.y;
    #pragma unroll
    for (int i = 0; i < 32; i += 8)
      t[ty + i][tx] = f2bf(W[(size_t)(by + ty + i) * DMOD + bx + tx]);
    __syncthreads();
    #pragma unroll
    for (int i = 0; i < 32; i += 8)
      o[(size_t)(bx + ty + i) * DMOD + by + tx] = t[tx][ty + i];
  } else {
    // 1024 virtual blocks x 256 threads x 16 f32 = 4096*1024
    int cid = blockIdx.x + 32 * blockIdx.y;
    int tid1 = threadIdx.y * 32 + threadIdx.x;
    size_t i = ((size_t)cid * 256 + tid1) * 16;
    #pragma unroll
    for (int half = 0; half < 2; ++half) {
      float4 f0 = *(const float4*)(x + i + half * 8);
      float4 f1 = *(const float4*)(x + i + half * 8 + 4);
      uint4 o;
      o.x = pack2bf(f0.x, f0.y); o.y = pack2bf(f0.z, f0.w);
      o.z = pack2bf(f1.x, f1.y); o.w = pack2bf(f1.z, f1.w);
      *(uint4*)(xb + i + half * 8) = o;
    }
  }
}

// -------- QKV GEMM: [4096x1024]*[3072x1024]^T, BK=64, gload_lds + XOR swizzle --------
// Round-9: XCD-chunked bijective block swizzle (768 = 8 XCDs x 96; chunk = 8 tileM x
// 12 tileN): per-XCD working set 2MB A-panel + 3MB Bt-panel = 5MB (was 1MB + 6MB ->
// Bt thrashed the 4MB L2). Round-robin id->XCD assumed (matches observed attn locality).
__global__ __launch_bounds__(256, 3) void gemm_qkv(const u16* __restrict__ A,
                                                   const u16* __restrict__ Bt,
                                                   u16* __restrict__ Qo,
                                                   u16* __restrict__ Ko,
                                                   u16* __restrict__ Vo) {
  __shared__ __align__(16) u16 As[128 * 64];
  __shared__ __align__(16) u16 Bs[128 * 64];
  const int tid  = threadIdx.x;
  const int lane = tid & 63, wv = tid >> 6;
  const int wm   = wv >> 1, wn = wv & 1;
  const int lrow = lane & 15, quad = lane >> 4;

  // bijective XCD-chunk remap: bid -> (xcd, loc); chunk grid 4x2 of 8Mx12N tiles
  const int bid = blockIdx.x + 32 * blockIdx.y;     // 0..767
  const int xcd = bid & 7, loc = bid >> 3;          // loc 0..95
  const int lm = loc & 7, ln = loc >> 3;            // 8 x 12
  const int cM = xcd & 3, cN = xcd >> 2;            // 4 x 2 chunks
  const int tileM = (cM * 8 + lm) * 128;
  const int tileN = (cN * 12 + ln) * 128;

  const f32x4 fz = {0.f, 0.f, 0.f, 0.f};
  f32x4 acc[4][4];
  #pragma unroll
  for (int i = 0; i < 4; ++i)
    #pragma unroll
    for (int j = 0; j < 4; ++j) acc[i][j] = fz;

  for (int kt = 0; kt < DMOD; kt += 64) {
    if (kt) __syncthreads();           // previous compute done reading LDS
    #pragma unroll
    for (int i = 0; i < 4; ++i) {
      int idx = i * 256 + tid;         // 1024 chunks of 16B = 128 rows x 128B
      int r = idx >> 3, c = idx & 7;
      gload16(&A [(size_t)(tileM + r) * DMOD + kt + ((c ^ (r & 7)) << 3)], &As[idx * 8]);
      gload16(&Bt[(size_t)(tileN + r) * DMOD + kt + ((c ^ (r & 7)) << 3)], &Bs[idx * 8]);
    }
    __syncthreads();                   // barrier drains vmcnt -> tile visible

    #pragma unroll
    for (int kk = 0; kk < 2; ++kk) {
      bf16x8 af[4], bfr[4];
      #pragma unroll
      for (int mt = 0; mt < 4; ++mt)
        af[mt] = *(const bf16x8*)(&As[(wm * 64 + mt * 16 + lrow) * 64
                                      + (((kk * 4 + quad) ^ (lrow & 7)) << 3)]);
      #pragma unroll
      for (int nt = 0; nt < 4; ++nt)
        bfr[nt] = *(const bf16x8*)(&Bs[(wn * 64 + nt * 16 + lrow) * 64
                                       + (((kk * 4 + quad) ^ (lrow & 7)) << 3)]);
      #pragma unroll
      for (int mt = 0; mt < 4; ++mt)
        #pragma unroll
        for (int nt = 0; nt < 4; ++nt)
          acc[mt][nt] = __builtin_amdgcn_mfma_f32_16x16x32_bf16(af[mt], bfr[nt],
                                                                acc[mt][nt], 0, 0, 0);
    }
  }

  #pragma unroll
  for (int mt = 0; mt < 4; ++mt) {
    #pragma unroll
    for (int nt = 0; nt < 4; ++nt) {
      int gm0 = tileM + wm * 64 + mt * 16 + quad * 4;
      int gn  = tileN + wn * 64 + nt * 16 + lrow;
      int which = gn >> 10, col = gn & 1023;
      int bb = gm0 >> 11, srw0 = gm0 & (SEQ - 1);
      int hh = col >> 6, dki = col & (DKH - 1);
      size_t bhi = (size_t)(bb * NH + hh);
      if (which == 0) {
        #pragma unroll
        for (int r = 0; r < 4; ++r)
          Qo[(bhi * SEQ + srw0 + r) * DKH + dki] = f2bf(acc[mt][nt][r] * QSCALE);
      } else if (which == 1) {
        #pragma unroll
        for (int r = 0; r < 4; ++r)
          Ko[(bhi * SEQ + srw0 + r) * DKH + dki] = f2bf(acc[mt][nt][r]);
      } else {
        uint2 pk;
        pk.x = pack2bf(acc[mt][nt][0], acc[mt][nt][1]);
        pk.y = pack2bf(acc[mt][nt][2], acc[mt][nt][3]);
        *(uint2*)(&Vo[(((bhi * (SEQ / 4)) + (srw0 >> 2)) * DKH + dki) * 4]) = pk;
      }
    }
  }
}

// -------- out GEMM: [4096x1024]*[1024x1024]^T -> fp32, 128x64, BK=64, swizzled --------
__global__ __launch_bounds__(256, 3) void gemm_out(const u16* __restrict__ A,
                                                   const u16* __restrict__ Bt,
                                                   float* __restrict__ Co) {
  __shared__ __align__(16) u16 As[128 * 64];
  __shared__ __align__(16) u16 Bs[64 * 64];
  const int tid  = threadIdx.x;
  const int lane = tid & 63, wv = tid >> 6;
  const int wm   = wv & 1, wn = wv >> 1;
  const int lrow = lane & 15, quad = lane >> 4;
  const int tileM = blockIdx.x * 128, tileN = blockIdx.y * 64;

  const f32x4 fz = {0.f, 0.f, 0.f, 0.f};
  f32x4 acc[4][2];
  #pragma unroll
  for (int i = 0; i < 4; ++i) { acc[i][0] = fz; acc[i][1] = fz; }

  for (int kt = 0; kt < DMOD; kt += 64) {
    if (kt) __syncthreads();
    #pragma unroll
    for (int i = 0; i < 4; ++i) {
      int idx = i * 256 + tid;
      int r = idx >> 3, c = idx & 7;
      gload16(&A[(size_t)(tileM + r) * DMOD + kt + ((c ^ (r & 7)) << 3)], &As[idx * 8]);
    }
    #pragma unroll
    for (int i = 0; i < 2; ++i) {
      int idx = i * 256 + tid;         // 512 chunks = 64 rows x 128B
      int r = idx >> 3, c = idx & 7;
      gload16(&Bt[(size_t)(tileN + r) * DMOD + kt + ((c ^ (r & 7)) << 3)], &Bs[idx * 8]);
    }
    __syncthreads();

    #pragma unroll
    for (int kk = 0; kk < 2; ++kk) {
      bf16x8 af[4], bfr[2];
      #pragma unroll
      for (int mt = 0; mt < 4; ++mt)
        af[mt] = *(const bf16x8*)(&As[(wm * 64 + mt * 16 + lrow) * 64
                                      + (((kk * 4 + quad) ^ (lrow & 7)) << 3)]);
      #pragma unroll
      for (int nt = 0; nt < 2; ++nt)
        bfr[nt] = *(const bf16x8*)(&Bs[(wn * 32 + nt * 16 + lrow) * 64
                                       + (((kk * 4 + quad) ^ (lrow & 7)) << 3)]);
      #pragma unroll
      for (int mt = 0; mt < 4; ++mt)
        #pragma unroll
        for (int nt = 0; nt < 2; ++nt)
          acc[mt][nt] = __builtin_amdgcn_mfma_f32_16x16x32_bf16(af[mt], bfr[nt],
                                                                acc[mt][nt], 0, 0, 0);
    }
  }

  #pragma unroll
  for (int mt = 0; mt < 4; ++mt)
    #pragma unroll
    for (int nt = 0; nt < 2; ++nt)
      #pragma unroll
      for (int r = 0; r < 4; ++r) {
        int gm = tileM + wm * 64 + mt * 16 + quad * 4 + r;
        int gn = tileN + wn * 32 + nt * 16 + lrow;
        Co[(size_t)gm * DMOD + gn] = acc[mt][nt][r];
      }
}

// ------------- causal flash attention: split-k wave-groups, in-LDS combine -------------
// (round-7 structure, best measured — FROZEN)
#define OPAD 68

__global__ __launch_bounds__(256, 2) void attn_k(const u16* __restrict__ Q,
                                                 const u16* __restrict__ Kg,
                                                 const u16* __restrict__ Vg,
                                                 u16* __restrict__ Og) {
  __shared__ __align__(16) u16 Ksb[2][2][64 * 64];    // [group][dbuf], swizzled
  __shared__ __align__(16) u16 Vsb[2][2][16 * 256];
  __shared__ __align__(16) u16 Osc[64 * OPAD];        // f32[32][OPAD] / u16[64][OPAD]
  __shared__ float Lsc[32];

  const int tid  = threadIdx.x;
  const int lane = tid & 63, w = tid >> 6;            // w in 0..3
  const int g    = w >> 1,  wg = w & 1;               // group, wave-in-group
  const int lrow = lane & 15, quad = lane >> 4;
  const int bh = blockIdx.x, y = blockIdx.y;          // y in 0..15
  const int b = bh >> 4, h = bh & 15;
  const int qB = 31 - y;
  const int sAend = y >> 1;                           // qA's last step index

  const u16* Qbh = Q  + (size_t)bh * SEQ * DKH;
  const u16* Kbh = Kg + (size_t)bh * SEQ * DKH;
  const u16* Vbh = Vg + (size_t)bh * SEQ * DKH;       // [s/4][dk][4]

  const f32x4 fz = {0.f, 0.f, 0.f, 0.f};
  f32x4 oacc[2][4];
  float lsum[2];
  bf16x8 bq[2][2];

  // decode step s, group gg -> (q-tile, k-tile j, valid)
#define DEC(s_, g_, qt_, j_, v_)                                                   \
  { if ((s_) <= sAend) { qt_ = y;  j_ = 2 * (s_) + (g_);              v_ = (j_ <= y);  } \
    else               { qt_ = qB; j_ = 2 * ((s_) - sAend - 1) + (g_); v_ = (j_ <= qB); } }

  // stage 64-row k-tile j into group gg's buffer p (dest linear, src inverse-swizzled)
#define STAGE1(gg, p_, j_)                                                          \
  { _Pragma("unroll")                                                               \
    for (int i_ = 0; i_ < 2; ++i_) {                                                \
      int cD = i_ * 256 + tid; int r_ = cD >> 3, c_ = cD & 7;                       \
      gload16(&Kbh[(size_t)((j_) * 64 + r_) * DKH + ((c_ ^ (r_ & 7)) << 3)],        \
              &Ksb[gg][p_][cD * 8]); }                                              \
    _Pragma("unroll")                                                               \
    for (int i_ = 0; i_ < 2; ++i_) {                                                \
      int cD = i_ * 256 + tid; int sq_ = cD >> 5, c_ = cD & 31;                     \
      gload16(&Vbh[(size_t)((j_) * 16 + sq_) * 256 + ((c_ ^ (sq_ & 7)) << 3)],      \
              &Vsb[gg][p_][cD * 8]); } }

#define LOADQ(qt_)                                                                  \
  { _Pragma("unroll")                                                               \
    for (int s_ = 0; s_ < 2; ++s_)                                                  \
      _Pragma("unroll")                                                             \
      for (int kk_ = 0; kk_ < 2; ++kk_)                                             \
        bq[s_][kk_] = *(const bf16x8*)(&Qbh[(size_t)((qt_) * 64 + wg * 32 + s_ * 16 \
                                            + lrow) * DKH + kk_ * 32 + quad * 8]); }

  // per-q-tile epilogue: group1 -> LDS partials (2 phases), group0 combines+writes
  auto EPI = [&](int qt) {
    float ls[2];
    #pragma unroll
    for (int s2 = 0; s2 < 2; ++s2) {
      float v = lsum[s2];
      v += __shfl_xor(v, 16, 64);
      v += __shfl_xor(v, 32, 64);
      ls[s2] = v;
    }
    float* OscF = (float*)Osc;
    #pragma unroll
    for (int ph = 0; ph < 2; ++ph) {
      if (g == 1) {
        int srow = wg * 16 + lrow;
        #pragma unroll
        for (int d = 0; d < 4; ++d)
          *(f32x4*)(&OscF[srow * OPAD + d * 16 + quad * 4]) = oacc[ph][d];
        if (quad == 0) Lsc[srow] = ls[ph];
      }
      __syncthreads();
      if (g == 0) {
        int srow = wg * 16 + lrow;
        ls[ph] += Lsc[srow];
        #pragma unroll
        for (int d = 0; d < 4; ++d) {
          f32x4 ov = *(const f32x4*)(&OscF[srow * OPAD + d * 16 + quad * 4]);
          oacc[ph][d] += ov;
        }
      }
      __syncthreads();
    }
    if (g == 0) {
      #pragma unroll
      for (int s2 = 0; s2 < 2; ++s2) {
        float inv = 1.f / ls[s2];
        int row = wg * 32 + s2 * 16 + lrow;
        #pragma unroll
        for (int d = 0; d < 4; ++d) {
          uint2 pkk;
          pkk.x = pack2bf(oacc[s2][d][0] * inv, oacc[s2][d][1] * inv);
          pkk.y = pack2bf(oacc[s2][d][2] * inv, oacc[s2][d][3] * inv);
          *(uint2*)(&Osc[row * OPAD + d * 16 + quad * 4]) = pkk;
        }
      }
    }
    __syncthreads();
    #pragma unroll
    for (int k2 = 0; k2 < 2; ++k2) {
      int c2 = k2 * 256 + tid;                    // 512 chunks = 64 rows x 128B
      int row = c2 >> 3, ch = c2 & 7;
      uint4 vv = *(const uint4*)(&Osc[row * OPAD + ch * 8]);
      *(uint4*)(&Og[(size_t)(b * SEQ + qt * 64 + row) * DMOD + h * DKH + ch * 8]) = vv;
    }
  };

  // ---- prologue: stage step-0 tiles, load qA fragments ----
  { int qt0, j0; bool v0;
    DEC(0, 0, qt0, j0, v0); if (v0) STAGE1(0, 0, j0);
    DEC(0, 1, qt0, j0, v0); if (v0) STAGE1(1, 0, j0);
  }
  LOADQ(y);
  #pragma unroll
  for (int s2 = 0; s2 < 2; ++s2) {
    oacc[s2][0] = fz; oacc[s2][1] = fz; oacc[s2][2] = fz; oacc[s2][3] = fz;
    lsum[s2] = 0.f;
  }
  __syncthreads();                                 // drain -> step-0 tiles ready

  for (int s = 0; s <= 16; ++s) {
    const int p = s & 1;

    if (s < 16) {                                  // issue next-step tiles (both groups)
      int qtn, jn; bool vn;
      DEC(s + 1, 0, qtn, jn, vn); if (vn) STAGE1(0, p ^ 1, jn);
      DEC(s + 1, 1, qtn, jn, vn); if (vn) STAGE1(1, p ^ 1, jn);
    }

    int qt, j; bool valid;
    DEC(s, g, qt, j, valid);
    if (valid) {
      const u16* Ks = Ksb[g][p];
      const u16* Vs = Vsb[g][p];
      if (j < qt) {
        __builtin_amdgcn_s_setprio(1);
        f32x4 sacc[2][4];
        #pragma unroll
        for (int s2 = 0; s2 < 2; ++s2)
          #pragma unroll
          for (int m = 0; m < 4; ++m) sacc[s2][m] = fz;
        #pragma unroll
        for (int kk = 0; kk < 2; ++kk)
          #pragma unroll
          for (int m = 0; m < 4; ++m) {
            bf16x8 ak = *(const bf16x8*)(&Ks[(m * 16 + lrow) * 64
                                             + (((kk * 4 + quad) ^ (lrow & 7)) << 3)]);
            sacc[0][m] = __builtin_amdgcn_mfma_f32_16x16x32_bf16(ak, bq[0][kk], sacc[0][m], 0, 0, 0);
            sacc[1][m] = __builtin_amdgcn_mfma_f32_16x16x32_bf16(ak, bq[1][kk], sacc[1][m], 0, 0, 0);
          }
        #pragma unroll
        for (int m = 0; m < 4; ++m) {
          float p00 = EXP2(sacc[0][m][0]), p01 = EXP2(sacc[0][m][1]);
          float p02 = EXP2(sacc[0][m][2]), p03 = EXP2(sacc[0][m][3]);
          float p10 = EXP2(sacc[1][m][0]), p11 = EXP2(sacc[1][m][1]);
          float p12 = EXP2(sacc[1][m][2]), p13 = EXP2(sacc[1][m][3]);
          lsum[0] += (p00 + p01) + (p02 + p03);
          lsum[1] += (p10 + p11) + (p12 + p13);
          s16x4 pk0 = pk4bf(p00, p01, p02, p03);
          s16x4 pk1 = pk4bf(p10, p11, p12, p13);
          const int sq = m * 4 + quad;
          #pragma unroll
          for (int d = 0; d < 4; ++d) {
            int dk = d * 16 + lrow;
            s16x4 av = *(const s16x4*)(&Vs[sq * 256
                                           + ((((dk >> 1) ^ (sq & 7)) << 3) | ((dk & 1) << 2))]);
            oacc[0][d] = mfma16(av, pk0, oacc[0][d]);
            oacc[1][d] = mfma16(av, pk1, oacc[1][d]);
          }
        }
        __builtin_amdgcn_s_setprio(0);
      } else {
        // diagonal 64x64 tile: strip ss = 2*wg + s2; m<ss full, m==ss masked
        #pragma unroll
        for (int s2 = 0; s2 < 2; ++s2) {
          const int L = 2 * wg + s2;
          for (int m = 0; m < L; ++m) {
            f32x4 sv = fz;
            #pragma unroll
            for (int kk = 0; kk < 2; ++kk) {
              bf16x8 ak = *(const bf16x8*)(&Ks[(m * 16 + lrow) * 64
                                               + (((kk * 4 + quad) ^ (lrow & 7)) << 3)]);
              sv = __builtin_amdgcn_mfma_f32_16x16x32_bf16(ak, bq[s2][kk], sv, 0, 0, 0);
            }
            float p0 = EXP2(sv[0]), p1 = EXP2(sv[1]), p2 = EXP2(sv[2]), p3 = EXP2(sv[3]);
            lsum[s2] += (p0 + p1) + (p2 + p3);
            s16x4 pk = pk4bf(p0, p1, p2, p3);
            const int sq = m * 4 + quad;
            #pragma unroll
            for (int d = 0; d < 4; ++d) {
              int dk = d * 16 + lrow;
              s16x4 av = *(const s16x4*)(&Vs[sq * 256
                                             + ((((dk >> 1) ^ (sq & 7)) << 3) | ((dk & 1) << 2))]);
              oacc[s2][d] = mfma16(av, pk, oacc[s2][d]);
            }
          }
          { // m == L : masked strip (k > q -> 0)
            f32x4 sv = fz;
            #pragma unroll
            for (int kk = 0; kk < 2; ++kk) {
              bf16x8 ak = *(const bf16x8*)(&Ks[(L * 16 + lrow) * 64
                                               + (((kk * 4 + quad) ^ (lrow & 7)) << 3)]);
              sv = __builtin_amdgcn_mfma_f32_16x16x32_bf16(ak, bq[s2][kk], sv, 0, 0, 0);
            }
            float pp[4];
            #pragma unroll
            for (int r = 0; r < 4; ++r)
              pp[r] = (quad * 4 + r > lrow) ? 0.f : EXP2(sv[r]);
            lsum[s2] += (pp[0] + pp[1]) + (pp[2] + pp[3]);
            s16x4 pk = pk4bf(pp[0], pp[1], pp[2], pp[3]);
            const int sq = L * 4 + quad;
            #pragma unroll
            for (int d = 0; d < 4; ++d) {
              int dk = d * 16 + lrow;
              s16x4 av = *(const s16x4*)(&Vs[sq * 256
                                             + ((((dk >> 1) ^ (sq & 7)) << 3) | ((dk & 1) << 2))]);
              oacc[s2][d] = mfma16(av, pk, oacc[s2][d]);
            }
          }
        }
      }
    }

    __syncthreads();                               // step end: staged drained, compute done

    if (s == sAend) {
      EPI(y);                                      // combine + write qA
      #pragma unroll
      for (int s2 = 0; s2 < 2; ++s2) {
        oacc[s2][0] = fz; oacc[s2][1] = fz; oacc[s2][2] = fz; oacc[s2][3] = fz;
        lsum[s2] = 0.f;
      }
      LOADQ(qB);
    } else if (s == 16) {
      EPI(qB);
    }
  }
#undef DEC
#undef STAGE1
#undef LOADQ
}

// ---------------- launch ----------------
extern "C" void kernel_launch(void* const* d_in, const int* in_sizes, int n_in,
                              void* d_out, int out_size, void* d_ws, size_t ws_size,
                              hipStream_t stream) {
  const float* x  = (const float*)d_in[0];
  const float* Wq = (const float*)d_in[1];
  const float* Wk = (const float*)d_in[2];
  const float* Wv = (const float*)d_in[3];
  const float* Wo = (const float*)d_in[4];

  u16* ws = (u16*)d_ws;
  const size_t WSZ = (size_t)DMOD * DMOD;
  const size_t TSZ = (size_t)BAT * NH * SEQ * DKH;
  u16* Wt  = ws;                 // 4 transposed weights
  u16* Wto = Wt + 3 * WSZ;
  u16* xb  = Wt + 4 * WSZ;       // x bf16; dead after QKV -> reused as Ob
  u16* Qb  = xb + TSZ;
  u16* Kb  = Qb + TSZ;
  u16* Vb  = Kb + TSZ;           // [b,h,s/4,dk,4]
  u16* Ob  = xb;

  prep<<<dim3(32, 32, 5), dim3(32, 8), 0, stream>>>(Wq, Wk, Wv, Wo, Wt, x, xb);

  gemm_qkv<<<dim3(32, 24), 256, 0, stream>>>(xb, Wt, Qb, Kb, Vb);

  attn_k<<<dim3(32, 16), 256, 0, stream>>>(Qb, Kb, Vb, Ob);

  gemm_out<<<dim3(32, 16), 256, 0, stream>>>(Ob, Wto, (float*)d_out);
}

// Round 10
// 159.565 us; speedup vs baseline: 1.0438x; 1.0438x over previous
//
#include <hip/hip_runtime.h>

typedef unsigned short u16;
typedef unsigned int   u32;

using bf16x8 = __attribute__((ext_vector_type(8))) __bf16;
using bf16x4 = __attribute__((ext_vector_type(4))) __bf16;
using f32x4  = __attribute__((ext_vector_type(4))) float;
using s16x4  = __attribute__((ext_vector_type(4))) short;

#define NH    16
#define DKH   64
#define SEQ   2048
#define BAT   2
#define DMOD  1024

// 0.125 (1/sqrt(dk)) * log2(e): scores in log2 domain -> p = exp2(s)
#define QSCALE 0.18033688011112042f

__device__ __forceinline__ u16 f2bf(float f) {
  union { float f; u32 u; } v; v.f = f;
  u32 r = v.u + 0x7fffu + ((v.u >> 16) & 1u);
  return (u16)(r >> 16);
}

__device__ __forceinline__ u32 pack2bf(float a, float b) {
  union { float f; u32 u; } x, y; x.f = a; y.f = b;
  u32 ua = x.u + 0x7fffu + ((x.u >> 16) & 1u);
  u32 ub = y.u + 0x7fffu + ((y.u >> 16) & 1u);
  return __builtin_amdgcn_perm(ub, ua, 0x07060302u);
}

// compiler emits v_cvt_pk_bf16_f32 pairs
__device__ __forceinline__ s16x4 pk4bf(float a, float b, float c, float d) {
  union { bf16x4 bv; s16x4 sv; } u;
  u.bv[0] = (__bf16)a; u.bv[1] = (__bf16)b; u.bv[2] = (__bf16)c; u.bv[3] = (__bf16)d;
  return u.sv;
}

#if __has_builtin(__builtin_amdgcn_exp2f)
#define EXP2(x) __builtin_amdgcn_exp2f(x)
#else
#define EXP2(x) exp2f(x)
#endif

#if __has_builtin(__builtin_amdgcn_mfma_f32_16x16x16bf16_1k)
__device__ __forceinline__ f32x4 mfma16(s16x4 a, s16x4 b, f32x4 c) {
  return __builtin_amdgcn_mfma_f32_16x16x16bf16_1k(a, b, c, 0, 0, 0);
}
#else
__device__ __forceinline__ f32x4 mfma16(s16x4 a, s16x4 b, f32x4 c) {
  f32x4 d;
  asm volatile("v_mfma_f32_16x16x16_bf16 %0, %1, %2, %3\n\ts_nop 7\n\ts_nop 7"
               : "=v"(d) : "v"(a), "v"(b), "v"(c));
  return d;
}
#endif

// async global->LDS, 16B per lane. Dest must be linear in tid within each wave.
typedef const __attribute__((address_space(1))) u32 glb_u32;
typedef __attribute__((address_space(3))) u32 lds_u32;
__device__ __forceinline__ void gload16(const u16* g, u16* l) {
  __builtin_amdgcn_global_load_lds((glb_u32*)(const void*)g, (lds_u32*)(void*)l, 16, 0, 0);
}

// -------- fused prep: 4x weight transpose+cvt (z<4) + x fp32->bf16 (z==4) --------
// (kept from round 9: one launch instead of two; mechanism is launch-count, safe)
__global__ __launch_bounds__(256) void prep(const float* __restrict__ Wq,
                                            const float* __restrict__ Wk,
                                            const float* __restrict__ Wv,
                                            const float* __restrict__ Wo,
                                            u16* __restrict__ Wt,
                                            const float* __restrict__ x,
                                            u16* __restrict__ xb) {
  const int z = blockIdx.z;
  if (z < 4) {
    __shared__ u16 t[32][33];
    const float* W = z == 0 ? Wq : z == 1 ? Wk : z == 2 ? Wv : Wo;
    u16* o = Wt + (size_t)z * DMOD * DMOD;
    int bx = blockIdx.x * 32, by = blockIdx.y * 32;
    int tx = threadIdx.x, ty = threadIdx.y;
    #pragma unroll
    for (int i = 0; i < 32; i += 8)
      t[ty + i][tx] = f2bf(W[(size_t)(by + ty + i) * DMOD + bx + tx]);
    __syncthreads();
    #pragma unroll
    for (int i = 0; i < 32; i += 8)
      o[(size_t)(bx + ty + i) * DMOD + by + tx] = t[tx][ty + i];
  } else {
    // 1024 virtual blocks x 256 threads x 16 f32 = 4096*1024
    int cid = blockIdx.x + 32 * blockIdx.y;
    int tid1 = threadIdx.y * 32 + threadIdx.x;
    size_t i = ((size_t)cid * 256 + tid1) * 16;
    #pragma unroll
    for (int half = 0; half < 2; ++half) {
      float4 f0 = *(const float4*)(x + i + half * 8);
      float4 f1 = *(const float4*)(x + i + half * 8 + 4);
      uint4 o;
      o.x = pack2bf(f0.x, f0.y); o.y = pack2bf(f0.z, f0.w);
      o.z = pack2bf(f1.x, f1.y); o.w = pack2bf(f1.z, f1.w);
      *(uint4*)(xb + i + half * 8) = o;
    }
  }
}

// -------- QKV GEMM: [4096x1024]*[3072x1024]^T, BK=64, gload_lds + XOR swizzle --------
// Round-10: REVERTED to round-8 linear block mapping (round-9's XCD-chunk remap was
// the suspected regression: its round-robin-placement premise is unverified, and the
// panels are L2/L3-resident so T1's HBM-bound mechanism had nothing to gain).
__global__ __launch_bounds__(256, 3) void gemm_qkv(const u16* __restrict__ A,
                                                   const u16* __restrict__ Bt,
                                                   u16* __restrict__ Qo,
                                                   u16* __restrict__ Ko,
                                                   u16* __restrict__ Vo) {
  __shared__ __align__(16) u16 As[128 * 64];
  __shared__ __align__(16) u16 Bs[128 * 64];
  const int tid  = threadIdx.x;
  const int lane = tid & 63, wv = tid >> 6;
  const int wm   = wv >> 1, wn = wv & 1;
  const int lrow = lane & 15, quad = lane >> 4;
  const int tileM = blockIdx.x * 128, tileN = blockIdx.y * 128;

  const f32x4 fz = {0.f, 0.f, 0.f, 0.f};
  f32x4 acc[4][4];
  #pragma unroll
  for (int i = 0; i < 4; ++i)
    #pragma unroll
    for (int j = 0; j < 4; ++j) acc[i][j] = fz;

  for (int kt = 0; kt < DMOD; kt += 64) {
    if (kt) __syncthreads();           // previous compute done reading LDS
    #pragma unroll
    for (int i = 0; i < 4; ++i) {
      int idx = i * 256 + tid;         // 1024 chunks of 16B = 128 rows x 128B
      int r = idx >> 3, c = idx & 7;
      gload16(&A [(size_t)(tileM + r) * DMOD + kt + ((c ^ (r & 7)) << 3)], &As[idx * 8]);
      gload16(&Bt[(size_t)(tileN + r) * DMOD + kt + ((c ^ (r & 7)) << 3)], &Bs[idx * 8]);
    }
    __syncthreads();                   // barrier drains vmcnt -> tile visible

    #pragma unroll
    for (int kk = 0; kk < 2; ++kk) {
      bf16x8 af[4], bfr[4];
      #pragma unroll
      for (int mt = 0; mt < 4; ++mt)
        af[mt] = *(const bf16x8*)(&As[(wm * 64 + mt * 16 + lrow) * 64
                                      + (((kk * 4 + quad) ^ (lrow & 7)) << 3)]);
      #pragma unroll
      for (int nt = 0; nt < 4; ++nt)
        bfr[nt] = *(const bf16x8*)(&Bs[(wn * 64 + nt * 16 + lrow) * 64
                                       + (((kk * 4 + quad) ^ (lrow & 7)) << 3)]);
      #pragma unroll
      for (int mt = 0; mt < 4; ++mt)
        #pragma unroll
        for (int nt = 0; nt < 4; ++nt)
          acc[mt][nt] = __builtin_amdgcn_mfma_f32_16x16x32_bf16(af[mt], bfr[nt],
                                                                acc[mt][nt], 0, 0, 0);
    }
  }

  #pragma unroll
  for (int mt = 0; mt < 4; ++mt) {
    #pragma unroll
    for (int nt = 0; nt < 4; ++nt) {
      int gm0 = tileM + wm * 64 + mt * 16 + quad * 4;
      int gn  = tileN + wn * 64 + nt * 16 + lrow;
      int which = gn >> 10, col = gn & 1023;
      int bb = gm0 >> 11, srw0 = gm0 & (SEQ - 1);
      int hh = col >> 6, dki = col & (DKH - 1);
      size_t bhi = (size_t)(bb * NH + hh);
      if (which == 0) {
        #pragma unroll
        for (int r = 0; r < 4; ++r)
          Qo[(bhi * SEQ + srw0 + r) * DKH + dki] = f2bf(acc[mt][nt][r] * QSCALE);
      } else if (which == 1) {
        #pragma unroll
        for (int r = 0; r < 4; ++r)
          Ko[(bhi * SEQ + srw0 + r) * DKH + dki] = f2bf(acc[mt][nt][r]);
      } else {
        uint2 pk;
        pk.x = pack2bf(acc[mt][nt][0], acc[mt][nt][1]);
        pk.y = pack2bf(acc[mt][nt][2], acc[mt][nt][3]);
        *(uint2*)(&Vo[(((bhi * (SEQ / 4)) + (srw0 >> 2)) * DKH + dki) * 4]) = pk;
      }
    }
  }
}

// -------- out GEMM: [4096x1024]*[1024x1024]^T -> fp32, 128x64, BK=64, swizzled --------
__global__ __launch_bounds__(256, 3) void gemm_out(const u16* __restrict__ A,
                                                   const u16* __restrict__ Bt,
                                                   float* __restrict__ Co) {
  __shared__ __align__(16) u16 As[128 * 64];
  __shared__ __align__(16) u16 Bs[64 * 64];
  const int tid  = threadIdx.x;
  const int lane = tid & 63, wv = tid >> 6;
  const int wm   = wv & 1, wn = wv >> 1;
  const int lrow = lane & 15, quad = lane >> 4;
  const int tileM = blockIdx.x * 128, tileN = blockIdx.y * 64;

  const f32x4 fz = {0.f, 0.f, 0.f, 0.f};
  f32x4 acc[4][2];
  #pragma unroll
  for (int i = 0; i < 4; ++i) { acc[i][0] = fz; acc[i][1] = fz; }

  for (int kt = 0; kt < DMOD; kt += 64) {
    if (kt) __syncthreads();
    #pragma unroll
    for (int i = 0; i < 4; ++i) {
      int idx = i * 256 + tid;
      int r = idx >> 3, c = idx & 7;
      gload16(&A[(size_t)(tileM + r) * DMOD + kt + ((c ^ (r & 7)) << 3)], &As[idx * 8]);
    }
    #pragma unroll
    for (int i = 0; i < 2; ++i) {
      int idx = i * 256 + tid;         // 512 chunks = 64 rows x 128B
      int r = idx >> 3, c = idx & 7;
      gload16(&Bt[(size_t)(tileN + r) * DMOD + kt + ((c ^ (r & 7)) << 3)], &Bs[idx * 8]);
    }
    __syncthreads();

    #pragma unroll
    for (int kk = 0; kk < 2; ++kk) {
      bf16x8 af[4], bfr[2];
      #pragma unroll
      for (int mt = 0; mt < 4; ++mt)
        af[mt] = *(const bf16x8*)(&As[(wm * 64 + mt * 16 + lrow) * 64
                                      + (((kk * 4 + quad) ^ (lrow & 7)) << 3)]);
      #pragma unroll
      for (int nt = 0; nt < 2; ++nt)
        bfr[nt] = *(const bf16x8*)(&Bs[(wn * 32 + nt * 16 + lrow) * 64
                                       + (((kk * 4 + quad) ^ (lrow & 7)) << 3)]);
      #pragma unroll
      for (int mt = 0; mt < 4; ++mt)
        #pragma unroll
        for (int nt = 0; nt < 2; ++nt)
          acc[mt][nt] = __builtin_amdgcn_mfma_f32_16x16x32_bf16(af[mt], bfr[nt],
                                                                acc[mt][nt], 0, 0, 0);
    }
  }

  #pragma unroll
  for (int mt = 0; mt < 4; ++mt)
    #pragma unroll
    for (int nt = 0; nt < 2; ++nt)
      #pragma unroll
      for (int r = 0; r < 4; ++r) {
        int gm = tileM + wm * 64 + mt * 16 + quad * 4 + r;
        int gn = tileN + wn * 32 + nt * 16 + lrow;
        Co[(size_t)gm * DMOD + gn] = acc[mt][nt][r];
      }
}

// ------------- causal flash attention: split-k wave-groups, in-LDS combine -------------
// (round-7 structure, best measured — FROZEN)
#define OPAD 68

__global__ __launch_bounds__(256, 2) void attn_k(const u16* __restrict__ Q,
                                                 const u16* __restrict__ Kg,
                                                 const u16* __restrict__ Vg,
                                                 u16* __restrict__ Og) {
  __shared__ __align__(16) u16 Ksb[2][2][64 * 64];    // [group][dbuf], swizzled
  __shared__ __align__(16) u16 Vsb[2][2][16 * 256];
  __shared__ __align__(16) u16 Osc[64 * OPAD];        // f32[32][OPAD] / u16[64][OPAD]
  __shared__ float Lsc[32];

  const int tid  = threadIdx.x;
  const int lane = tid & 63, w = tid >> 6;            // w in 0..3
  const int g    = w >> 1,  wg = w & 1;               // group, wave-in-group
  const int lrow = lane & 15, quad = lane >> 4;
  const int bh = blockIdx.x, y = blockIdx.y;          // y in 0..15
  const int b = bh >> 4, h = bh & 15;
  const int qB = 31 - y;
  const int sAend = y >> 1;                           // qA's last step index

  const u16* Qbh = Q  + (size_t)bh * SEQ * DKH;
  const u16* Kbh = Kg + (size_t)bh * SEQ * DKH;
  const u16* Vbh = Vg + (size_t)bh * SEQ * DKH;       // [s/4][dk][4]

  const f32x4 fz = {0.f, 0.f, 0.f, 0.f};
  f32x4 oacc[2][4];
  float lsum[2];
  bf16x8 bq[2][2];

  // decode step s, group gg -> (q-tile, k-tile j, valid)
#define DEC(s_, g_, qt_, j_, v_)                                                   \
  { if ((s_) <= sAend) { qt_ = y;  j_ = 2 * (s_) + (g_);              v_ = (j_ <= y);  } \
    else               { qt_ = qB; j_ = 2 * ((s_) - sAend - 1) + (g_); v_ = (j_ <= qB); } }

  // stage 64-row k-tile j into group gg's buffer p (dest linear, src inverse-swizzled)
#define STAGE1(gg, p_, j_)                                                          \
  { _Pragma("unroll")                                                               \
    for (int i_ = 0; i_ < 2; ++i_) {                                                \
      int cD = i_ * 256 + tid; int r_ = cD >> 3, c_ = cD & 7;                       \
      gload16(&Kbh[(size_t)((j_) * 64 + r_) * DKH + ((c_ ^ (r_ & 7)) << 3)],        \
              &Ksb[gg][p_][cD * 8]); }                                              \
    _Pragma("unroll")                                                               \
    for (int i_ = 0; i_ < 2; ++i_) {                                                \
      int cD = i_ * 256 + tid; int sq_ = cD >> 5, c_ = cD & 31;                     \
      gload16(&Vbh[(size_t)((j_) * 16 + sq_) * 256 + ((c_ ^ (sq_ & 7)) << 3)],      \
              &Vsb[gg][p_][cD * 8]); } }

#define LOADQ(qt_)                                                                  \
  { _Pragma("unroll")                                                               \
    for (int s_ = 0; s_ < 2; ++s_)                                                  \
      _Pragma("unroll")                                                             \
      for (int kk_ = 0; kk_ < 2; ++kk_)                                             \
        bq[s_][kk_] = *(const bf16x8*)(&Qbh[(size_t)((qt_) * 64 + wg * 32 + s_ * 16 \
                                            + lrow) * DKH + kk_ * 32 + quad * 8]); }

  // per-q-tile epilogue: group1 -> LDS partials (2 phases), group0 combines+writes
  auto EPI = [&](int qt) {
    float ls[2];
    #pragma unroll
    for (int s2 = 0; s2 < 2; ++s2) {
      float v = lsum[s2];
      v += __shfl_xor(v, 16, 64);
      v += __shfl_xor(v, 32, 64);
      ls[s2] = v;
    }
    float* OscF = (float*)Osc;
    #pragma unroll
    for (int ph = 0; ph < 2; ++ph) {
      if (g == 1) {
        int srow = wg * 16 + lrow;
        #pragma unroll
        for (int d = 0; d < 4; ++d)
          *(f32x4*)(&OscF[srow * OPAD + d * 16 + quad * 4]) = oacc[ph][d];
        if (quad == 0) Lsc[srow] = ls[ph];
      }
      __syncthreads();
      if (g == 0) {
        int srow = wg * 16 + lrow;
        ls[ph] += Lsc[srow];
        #pragma unroll
        for (int d = 0; d < 4; ++d) {
          f32x4 ov = *(const f32x4*)(&OscF[srow * OPAD + d * 16 + quad * 4]);
          oacc[ph][d] += ov;
        }
      }
      __syncthreads();
    }
    if (g == 0) {
      #pragma unroll
      for (int s2 = 0; s2 < 2; ++s2) {
        float inv = 1.f / ls[s2];
        int row = wg * 32 + s2 * 16 + lrow;
        #pragma unroll
        for (int d = 0; d < 4; ++d) {
          uint2 pkk;
          pkk.x = pack2bf(oacc[s2][d][0] * inv, oacc[s2][d][1] * inv);
          pkk.y = pack2bf(oacc[s2][d][2] * inv, oacc[s2][d][3] * inv);
          *(uint2*)(&Osc[row * OPAD + d * 16 + quad * 4]) = pkk;
        }
      }
    }
    __syncthreads();
    #pragma unroll
    for (int k2 = 0; k2 < 2; ++k2) {
      int c2 = k2 * 256 + tid;                    // 512 chunks = 64 rows x 128B
      int row = c2 >> 3, ch = c2 & 7;
      uint4 vv = *(const uint4*)(&Osc[row * OPAD + ch * 8]);
      *(uint4*)(&Og[(size_t)(b * SEQ + qt * 64 + row) * DMOD + h * DKH + ch * 8]) = vv;
    }
  };

  // ---- prologue: stage step-0 tiles, load qA fragments ----
  { int qt0, j0; bool v0;
    DEC(0, 0, qt0, j0, v0); if (v0) STAGE1(0, 0, j0);
    DEC(0, 1, qt0, j0, v0); if (v0) STAGE1(1, 0, j0);
  }
  LOADQ(y);
  #pragma unroll
  for (int s2 = 0; s2 < 2; ++s2) {
    oacc[s2][0] = fz; oacc[s2][1] = fz; oacc[s2][2] = fz; oacc[s2][3] = fz;
    lsum[s2] = 0.f;
  }
  __syncthreads();                                 // drain -> step-0 tiles ready

  for (int s = 0; s <= 16; ++s) {
    const int p = s & 1;

    if (s < 16) {                                  // issue next-step tiles (both groups)
      int qtn, jn; bool vn;
      DEC(s + 1, 0, qtn, jn, vn); if (vn) STAGE1(0, p ^ 1, jn);
      DEC(s + 1, 1, qtn, jn, vn); if (vn) STAGE1(1, p ^ 1, jn);
    }

    int qt, j; bool valid;
    DEC(s, g, qt, j, valid);
    if (valid) {
      const u16* Ks = Ksb[g][p];
      const u16* Vs = Vsb[g][p];
      if (j < qt) {
        __builtin_amdgcn_s_setprio(1);
        f32x4 sacc[2][4];
        #pragma unroll
        for (int s2 = 0; s2 < 2; ++s2)
          #pragma unroll
          for (int m = 0; m < 4; ++m) sacc[s2][m] = fz;
        #pragma unroll
        for (int kk = 0; kk < 2; ++kk)
          #pragma unroll
          for (int m = 0; m < 4; ++m) {
            bf16x8 ak = *(const bf16x8*)(&Ks[(m * 16 + lrow) * 64
                                             + (((kk * 4 + quad) ^ (lrow & 7)) << 3)]);
            sacc[0][m] = __builtin_amdgcn_mfma_f32_16x16x32_bf16(ak, bq[0][kk], sacc[0][m], 0, 0, 0);
            sacc[1][m] = __builtin_amdgcn_mfma_f32_16x16x32_bf16(ak, bq[1][kk], sacc[1][m], 0, 0, 0);
          }
        #pragma unroll
        for (int m = 0; m < 4; ++m) {
          float p00 = EXP2(sacc[0][m][0]), p01 = EXP2(sacc[0][m][1]);
          float p02 = EXP2(sacc[0][m][2]), p03 = EXP2(sacc[0][m][3]);
          float p10 = EXP2(sacc[1][m][0]), p11 = EXP2(sacc[1][m][1]);
          float p12 = EXP2(sacc[1][m][2]), p13 = EXP2(sacc[1][m][3]);
          lsum[0] += (p00 + p01) + (p02 + p03);
          lsum[1] += (p10 + p11) + (p12 + p13);
          s16x4 pk0 = pk4bf(p00, p01, p02, p03);
          s16x4 pk1 = pk4bf(p10, p11, p12, p13);
          const int sq = m * 4 + quad;
          #pragma unroll
          for (int d = 0; d < 4; ++d) {
            int dk = d * 16 + lrow;
            s16x4 av = *(const s16x4*)(&Vs[sq * 256
                                           + ((((dk >> 1) ^ (sq & 7)) << 3) | ((dk & 1) << 2))]);
            oacc[0][d] = mfma16(av, pk0, oacc[0][d]);
            oacc[1][d] = mfma16(av, pk1, oacc[1][d]);
          }
        }
        __builtin_amdgcn_s_setprio(0);
      } else {
        // diagonal 64x64 tile: strip ss = 2*wg + s2; m<ss full, m==ss masked
        #pragma unroll
        for (int s2 = 0; s2 < 2; ++s2) {
          const int L = 2 * wg + s2;
          for (int m = 0; m < L; ++m) {
            f32x4 sv = fz;
            #pragma unroll
            for (int kk = 0; kk < 2; ++kk) {
              bf16x8 ak = *(const bf16x8*)(&Ks[(m * 16 + lrow) * 64
                                               + (((kk * 4 + quad) ^ (lrow & 7)) << 3)]);
              sv = __builtin_amdgcn_mfma_f32_16x16x32_bf16(ak, bq[s2][kk], sv, 0, 0, 0);
            }
            float p0 = EXP2(sv[0]), p1 = EXP2(sv[1]), p2 = EXP2(sv[2]), p3 = EXP2(sv[3]);
            lsum[s2] += (p0 + p1) + (p2 + p3);
            s16x4 pk = pk4bf(p0, p1, p2, p3);
            const int sq = m * 4 + quad;
            #pragma unroll
            for (int d = 0; d < 4; ++d) {
              int dk = d * 16 + lrow;
              s16x4 av = *(const s16x4*)(&Vs[sq * 256
                                             + ((((dk >> 1) ^ (sq & 7)) << 3) | ((dk & 1) << 2))]);
              oacc[s2][d] = mfma16(av, pk, oacc[s2][d]);
            }
          }
          { // m == L : masked strip (k > q -> 0)
            f32x4 sv = fz;
            #pragma unroll
            for (int kk = 0; kk < 2; ++kk) {
              bf16x8 ak = *(const bf16x8*)(&Ks[(L * 16 + lrow) * 64
                                               + (((kk * 4 + quad) ^ (lrow & 7)) << 3)]);
              sv = __builtin_amdgcn_mfma_f32_16x16x32_bf16(ak, bq[s2][kk], sv, 0, 0, 0);
            }
            float pp[4];
            #pragma unroll
            for (int r = 0; r < 4; ++r)
              pp[r] = (quad * 4 + r > lrow) ? 0.f : EXP2(sv[r]);
            lsum[s2] += (pp[0] + pp[1]) + (pp[2] + pp[3]);
            s16x4 pk = pk4bf(pp[0], pp[1], pp[2], pp[3]);
            const int sq = L * 4 + quad;
            #pragma unroll
            for (int d = 0; d < 4; ++d) {
              int dk = d * 16 + lrow;
              s16x4 av = *(const s16x4*)(&Vs[sq * 256
                                             + ((((dk >> 1) ^ (sq & 7)) << 3) | ((dk & 1) << 2))]);
              oacc[s2][d] = mfma16(av, pk, oacc[s2][d]);
            }
          }
        }
      }
    }

    __syncthreads();                               // step end: staged drained, compute done

    if (s == sAend) {
      EPI(y);                                      // combine + write qA
      #pragma unroll
      for (int s2 = 0; s2 < 2; ++s2) {
        oacc[s2][0] = fz; oacc[s2][1] = fz; oacc[s2][2] = fz; oacc[s2][3] = fz;
        lsum[s2] = 0.f;
      }
      LOADQ(qB);
    } else if (s == 16) {
      EPI(qB);
    }
  }
#undef DEC
#undef STAGE1
#undef LOADQ
}

// ---------------- launch ----------------
extern "C" void kernel_launch(void* const* d_in, const int* in_sizes, int n_in,
                              void* d_out, int out_size, void* d_ws, size_t ws_size,
                              hipStream_t stream) {
  const float* x  = (const float*)d_in[0];
  const float* Wq = (const float*)d_in[1];
  const float* Wk = (const float*)d_in[2];
  const float* Wv = (const float*)d_in[3];
  const float* Wo = (const float*)d_in[4];

  u16* ws = (u16*)d_ws;
  const size_t WSZ = (size_t)DMOD * DMOD;
  const size_t TSZ = (size_t)BAT * NH * SEQ * DKH;
  u16* Wt  = ws;                 // 4 transposed weights
  u16* Wto = Wt + 3 * WSZ;
  u16* xb  = Wt + 4 * WSZ;       // x bf16; dead after QKV -> reused as Ob
  u16* Qb  = xb + TSZ;
  u16* Kb  = Qb + TSZ;
  u16* Vb  = Kb + TSZ;           // [b,h,s/4,dk,4]
  u16* Ob  = xb;

  prep<<<dim3(32, 32, 5), dim3(32, 8), 0, stream>>>(Wq, Wk, Wv, Wo, Wt, x, xb);

  gemm_qkv<<<dim3(32, 24), 256, 0, stream>>>(xb, Wt, Qb, Kb, Vb);

  attn_k<<<dim3(32, 16), 256, 0, stream>>>(Qb, Kb, Vb, Ob);

  gemm_out<<<dim3(32, 16), 256, 0, stream>>>(Ob, Wto, (float*)d_out);
}